// Round 9
// baseline (227.594 us; speedup 1.0000x reference)
//
#include <hip/hip_runtime.h>

// SpatialAttention G=2,N=192,D=64,H=4,DK=16 — round 9: DIAGNOSTIC build.
// Identical to round-8 kernel, but body repeated nrep(=2) times (runtime arg)
// so the dispatch exceeds the harness's ~45us fill dispatches and appears in
// rocprof top-5 with counters. Output identical (second rep rewrites it).

typedef float    f32x4 __attribute__((ext_vector_type(4)));
typedef float    f32x2 __attribute__((ext_vector_type(2)));
typedef _Float16 f16x2 __attribute__((ext_vector_type(2)));
typedef _Float16 f16x4 __attribute__((ext_vector_type(4)));
typedef _Float16 f16x8 __attribute__((ext_vector_type(8)));

__device__ __forceinline__ int xsw64(int r, int c) {
    return (r << 6) + (((c >> 3) ^ (r & 7)) << 3) + (c & 7);
}
__device__ __forceinline__ int vsw192(int r, int c) {
    return r * 192 + ((((c >> 3) ^ (r & 7)) & 31) << 3) + (c & 7);
}

#define QSCALE 0.36067376022224085f  /* 0.25 * log2(e) */

extern "C" __global__ void __launch_bounds__(512, 3)
spa_mfma5(const float* __restrict__ adj,
          const float* __restrict__ Wq, const float* __restrict__ bq,
          const float* __restrict__ Wk, const float* __restrict__ bk,
          const float* __restrict__ Wv, const float* __restrict__ bv,
          const float* __restrict__ Wo, const float* __restrict__ bo,
          float* __restrict__ out, int nrep) {
    extern __shared__ __align__(16) char smem[];
    _Float16* X  = (_Float16*)smem;           // [192][64] xsw64
    _Float16* VT = (_Float16*)smem + 12288;   // [64][192] vsw192

    const int tid = threadIdx.x;
    const int l   = tid & 63;
    const int wv  = tid >> 6;
    const int l15 = l & 15;
    const int g   = l >> 4;

    const float* Xg   = adj + (size_t)blockIdx.x * (192 * 64);
    float*       outg = out + (size_t)blockIdx.x * (192 * 64);

    const int h  = wv >> 1;
    const int eh = h << 4;
    const int et = wv & 3;
    const int ew = eh + l15;
    const int ev = ((wv & 3) << 4) + l15;

    // ---- W fragments: gathered from global (L2-broadcast), f32->f16 ----
    f16x8 wq0, wq1, wk0, wk1, wvv0, wvv1, wo0, wo1;
#pragma unroll
    for (int jd = 0; jd < 8; ++jd) {
        const int d0 = (g << 3) + jd;
        wq0[jd]  = (_Float16)(Wq[d0 * 64 + ew] * QSCALE);
        wq1[jd]  = (_Float16)(Wq[(32 + d0) * 64 + ew] * QSCALE);
        wk0[jd]  = (_Float16)(Wk[d0 * 64 + ew]);
        wk1[jd]  = (_Float16)(Wk[(32 + d0) * 64 + ew]);
        wvv0[jd] = (_Float16)(Wv[d0 * 64 + ev]);
        wvv1[jd] = (_Float16)(Wv[(32 + d0) * 64 + ev]);
        wo0[jd]  = (_Float16)(Wo[d0 * 64 + ev]);
        wo1[jd]  = (_Float16)(Wo[(32 + d0) * 64 + ev]);
    }
    f32x4 bq4 = *(const f32x4*)&bq[eh + (g << 2)];
#pragma unroll
    for (int r = 0; r < 4; ++r) bq4[r] *= QSCALE;
    const f32x4 bk4 = *(const f32x4*)&bk[eh + (g << 2)];
    const f32x4 bv4 = *(const f32x4*)&bv[((wv & 3) << 4) + (g << 2)];
    const float bov = bo[ev];

    for (int rep = 0; rep < nrep; ++rep) {

    // ---- stage X -> f16 LDS ----
    {
        const int d0 = (tid & 7) << 3;
        const int t0 = tid >> 3;
#pragma unroll
        for (int p = 0; p < 3; ++p) {
            int t = t0 + (p << 6);
            const float4* src = (const float4*)&Xg[(t << 6) + d0];
            float4 v0 = src[0], v1 = src[1];
            f16x8 h8;
            h8[0]=(_Float16)v0.x; h8[1]=(_Float16)v0.y; h8[2]=(_Float16)v0.z; h8[3]=(_Float16)v0.w;
            h8[4]=(_Float16)v1.x; h8[5]=(_Float16)v1.y; h8[6]=(_Float16)v1.z; h8[7]=(_Float16)v1.w;
            *(f16x8*)&X[xsw64(t, d0)] = h8;
        }
    }
    __syncthreads();

    const f32x4 z = {0.f, 0.f, 0.f, 0.f};

    // ---- VT slice ----
    {
        const int stb = (wv >> 2) * 6;
        for (int s6 = 0; s6 < 6; ++s6) {
            int st = stb + s6;
            f16x8 x0 = *(const f16x8*)&X[xsw64((st << 4) + l15, g << 3)];
            f16x8 x1 = *(const f16x8*)&X[xsw64((st << 4) + l15, 32 + (g << 3))];
            f32x4 c = __builtin_amdgcn_mfma_f32_16x16x32_f16(wvv0, x0, z, 0, 0, 0);
            c = __builtin_amdgcn_mfma_f32_16x16x32_f16(wvv1, x1, c, 0, 0, 0);
            int s = (st << 4) + l15;
#pragma unroll
            for (int r = 0; r < 4; ++r)
                VT[vsw192((et << 4) + (g << 2) + r, s)] = (_Float16)(c[r] + bv4[r]);
        }
    }

    // ---- K fragments ----
    f16x4 kf[12];
#pragma unroll
    for (int st = 0; st < 12; ++st) {
        f16x8 x0 = *(const f16x8*)&X[xsw64((st << 4) + l15, g << 3)];
        f16x8 x1 = *(const f16x8*)&X[xsw64((st << 4) + l15, 32 + (g << 3))];
        f32x4 c = __builtin_amdgcn_mfma_f32_16x16x32_f16(wk0, x0, z, 0, 0, 0);
        c = __builtin_amdgcn_mfma_f32_16x16x32_f16(wk1, x1, c, 0, 0, 0);
#pragma unroll
        for (int r = 0; r < 4; ++r) kf[st][r] = (_Float16)(c[r] + bk4[r]);
    }

    // ---- Q fragments ----
    f16x4 qf[6];
    const int tloc = (wv & 1) * 6;
#pragma unroll
    for (int j = 0; j < 6; ++j) {
        int tt = tloc + j;
        f16x8 x0 = *(const f16x8*)&X[xsw64((tt << 4) + l15, g << 3)];
        f16x8 x1 = *(const f16x8*)&X[xsw64((tt << 4) + l15, 32 + (g << 3))];
        f32x4 c = __builtin_amdgcn_mfma_f32_16x16x32_f16(wq0, x0, z, 0, 0, 0);
        c = __builtin_amdgcn_mfma_f32_16x16x32_f16(wq1, x1, c, 0, 0, 0);
#pragma unroll
        for (int r = 0; r < 4; ++r) qf[j][r] = (_Float16)(c[r] + bq4[r]);
    }
    __syncthreads();   // VT complete; X reads done

    // ---- vf: PV A-frags from VT ----
    f16x4 vf[12];
#pragma unroll
    for (int st = 0; st < 12; ++st)
        vf[st] = *(const f16x4*)&VT[vsw192(eh + l15, (st << 4) + (g << 2))];

    // ---- attention: 6 t-tiles, unrolled x2 ----
#pragma unroll
    for (int jj = 0; jj < 3; ++jj) {
        const int j0 = 2 * jj, j1 = 2 * jj + 1;
        f32x4 accA0 = z, accB0 = z, accA1 = z, accB1 = z;
        f32x2 rs0 = {0.f, 0.f}, rs1 = {0.f, 0.f};
#pragma unroll
        for (int st = 0; st < 12; ++st) {
            f32x4 c0 = __builtin_amdgcn_mfma_f32_16x16x16f16(kf[st], qf[j0], z, 0, 0, 0);
            f32x4 c1 = __builtin_amdgcn_mfma_f32_16x16x16f16(kf[st], qf[j1], z, 0, 0, 0);
            float p00 = exp2f(c0[0]), p01 = exp2f(c0[1]), p02 = exp2f(c0[2]), p03 = exp2f(c0[3]);
            float p10 = exp2f(c1[0]), p11 = exp2f(c1[1]), p12 = exp2f(c1[2]), p13 = exp2f(c1[3]);
            rs0 += (f32x2){p00, p01} + (f32x2){p02, p03};
            rs1 += (f32x2){p10, p11} + (f32x2){p12, p13};
            f16x2 lo0 = __builtin_bit_cast(f16x2, __builtin_amdgcn_cvt_pkrtz(p00, p01));
            f16x2 hi0 = __builtin_bit_cast(f16x2, __builtin_amdgcn_cvt_pkrtz(p02, p03));
            f16x2 lo1 = __builtin_bit_cast(f16x2, __builtin_amdgcn_cvt_pkrtz(p10, p11));
            f16x2 hi1 = __builtin_bit_cast(f16x2, __builtin_amdgcn_cvt_pkrtz(p12, p13));
            f16x4 pf0 = __builtin_shufflevector(lo0, hi0, 0, 1, 2, 3);
            f16x4 pf1 = __builtin_shufflevector(lo1, hi1, 0, 1, 2, 3);
            if (st & 1) {
                accB0 = __builtin_amdgcn_mfma_f32_16x16x16f16(vf[st], pf0, accB0, 0, 0, 0);
                accB1 = __builtin_amdgcn_mfma_f32_16x16x16f16(vf[st], pf1, accB1, 0, 0, 0);
            } else {
                accA0 = __builtin_amdgcn_mfma_f32_16x16x16f16(vf[st], pf0, accA0, 0, 0, 0);
                accA1 = __builtin_amdgcn_mfma_f32_16x16x16f16(vf[st], pf1, accA1, 0, 0, 0);
            }
        }
        float rsum0 = rs0[0] + rs0[1];
        float rsum1 = rs1[0] + rs1[1];
        rsum0 += __shfl_xor(rsum0, 16);
        rsum0 += __shfl_xor(rsum0, 32);
        rsum1 += __shfl_xor(rsum1, 16);
        rsum1 += __shfl_xor(rsum1, 32);
        const float rinv0 = 1.0f / rsum0;
        const float rinv1 = 1.0f / rsum1;
        f16x4 o0, o1;
#pragma unroll
        for (int r = 0; r < 4; ++r) {
            o0[r] = (_Float16)((accA0[r] + accB0[r]) * rinv0);
            o1[r] = (_Float16)((accA1[r] + accB1[r]) * rinv1);
        }
        *(f16x4*)&X[xsw64(((tloc + j0) << 4) + l15, eh + (g << 2))] = o0;
        *(f16x4*)&X[xsw64(((tloc + j1) << 4) + l15, eh + (g << 2))] = o1;
    }
    __syncthreads();

    // ---- O-projection -> global ----
    {
#pragma unroll
        for (int i = 0; i < 6; ++i) {
            int tt = (wv + (i << 3)) >> 2;
            f16x8 a0 = *(const f16x8*)&X[xsw64((tt << 4) + l15, g << 3)];
            f16x8 a1 = *(const f16x8*)&X[xsw64((tt << 4) + l15, 32 + (g << 3))];
            f32x4 c = __builtin_amdgcn_mfma_f32_16x16x32_f16(a0, wo0, z, 0, 0, 0);
            c = __builtin_amdgcn_mfma_f32_16x16x32_f16(a1, wo1, c, 0, 0, 0);
#pragma unroll
            for (int r = 0; r < 4; ++r)
                outg[(((tt << 4) + (g << 2) + r) << 6) + ev] = c[r] + bov;
        }
    }
    __syncthreads();   // all reads of X/VT done before next rep restages

    }  // rep
}

extern "C" void kernel_launch(void* const* d_in, const int* in_sizes, int n_in,
                              void* d_out, int out_size, void* d_ws, size_t ws_size,
                              hipStream_t stream) {
    (void)in_sizes; (void)n_in; (void)d_ws; (void)ws_size; (void)out_size;
    const int shmem = 49152;
    spa_mfma5<<<2 * 192, 512, shmem, stream>>>(
        (const float*)d_in[0],
        (const float*)d_in[1], (const float*)d_in[2],
        (const float*)d_in[3], (const float*)d_in[4],
        (const float*)d_in[5], (const float*)d_in[6],
        (const float*)d_in[7], (const float*)d_in[8],
        (float*)d_out, 2);
}